// Round 1
// 216.487 us; speedup vs baseline: 1.1748x; 1.1748x over previous
//
#include <hip/hip_runtime.h>

// ROIAlign3d: x=[2,256,16,64,64] f32, rois=[64,5] -> out=[64,256,16,7,7] f32.
// R4: block = (channel, roi, half-of-T). P=8 t-planes per block -> LDS 15.6KB
// -> 8 blocks/CU (100% occupancy). Staging trimmed to the exact nrows x ncol4
// float4 box actually sampled (uniform per block) instead of fixed 17x5.
// Grid is roi-inner so all 64 rois of ~16 channels are concurrently resident
// -> overlapping roi boxes on the same (c,t) plane hit L2.

#define NBINS 49
#define NSAMP 4
#define P     8             // t-planes per block (half of T)
#define MAXR  17            // worst-case rows in sample box
#define BW    20            // box row stride in floats (worst case 5 float4)
#define PSTR  (MAXR * BW)   // 340 floats per plane box

__global__ __launch_bounds__(256) void roialign3d_kernel(
    const float* __restrict__ x, const float* __restrict__ rois,
    float* __restrict__ out)
{
    constexpr int C = 256, T = 16, H = 64, W = 64;
    constexpr float SCALE = 0.0625f;
    constexpr int TOT = 2 * C * T * H * W;   // 33,554,432 elements

    __shared__ float  s_box[P * PSTR];       // 10,880 B
    __shared__ int2   s_off[NSAMP * NBINS];  //  1,568 B
    __shared__ float4 s_wt[NSAMP * NBINS];   //  3,136 B

    const int b   = blockIdx.x;
    const int c   = b >> 7;          // channel outer
    const int rg  = b & 127;         // roi inner -> cross-roi L2 reuse
    const int r   = rg >> 1;
    const int g   = rg & 1;          // which half of T
    const int tid = threadIdx.x;

    // ---- uniform roi params ----
    const float r1 = rois[r * 5 + 1], r2 = rois[r * 5 + 2];
    const float r3 = rois[r * 5 + 3], r4 = rois[r * 5 + 4];
    const int   bidx = (int)rois[r * 5 + 0];

    const float sw_ = r1 * SCALE, sh_ = r2 * SCALE;
    const float ew_ = r3 * SCALE, eh_ = r4 * SCALE;
    const float bin_w = fmaxf(ew_ - sw_, 1.0f) * (1.0f / 7.0f);
    const float bin_h = fmaxf(eh_ - sh_, 1.0f) * (1.0f / 7.0f);

    // exact sampled extents (samples monotone; first at +0.25*bin, last +6.75)
    const float ys_min = sh_ + 0.25f * bin_h, ys_max = sh_ + 6.75f * bin_h;
    const float xs_min = sw_ + 0.25f * bin_w, xs_max = sw_ + 6.75f * bin_w;
    const int y_lo  = (int)floorf(fminf(fmaxf(ys_min, 0.0f), (float)(H - 1)));
    const int y0mx  = (int)floorf(fminf(fmaxf(ys_max, 0.0f), (float)(H - 1)));
    const int x_lo  = (int)floorf(fminf(fmaxf(xs_min, 0.0f), (float)(W - 1)));
    const int x0mx  = (int)floorf(fminf(fmaxf(xs_max, 0.0f), (float)(W - 1)));
    const int x4_lo = x_lo & ~3;

    // rows needed: y_lo .. min(y0mx+1, H-1).  cols: through float4 containing
    // x0mx+1 (the +1 neighbor is always read, weight may be 0).
    const int nrows = min(y0mx + 1, H - 1) - y_lo + 1;        // <= 17
    const int ncol4 = ((x0mx + 1 - x4_lo) >> 2) + 1;          // <= 5

    // ---- sample table: 196 entries (threads 196..255 fall through) ----
    if (tid < NSAMP * NBINS) {
        const int s  = tid / NBINS;
        const int pp = tid - s * NBINS;
        const int ph = pp / 7, pw = pp - ph * 7;
        const float gyf = ((float)(s >> 1) + 0.5f) * 0.5f;
        const float gxf = ((float)(s & 1) + 0.5f) * 0.5f;

        const float ys = sh_ + ((float)ph + gyf) * bin_h;
        const float xs = sw_ + ((float)pw + gxf) * bin_w;

        const bool vy = (ys >= -1.0f) && (ys <= (float)H);
        const bool vx = (xs >= -1.0f) && (xs <= (float)W);

        const float yc = fminf(fmaxf(ys, 0.0f), (float)(H - 1));
        const int   y0 = (int)floorf(yc);
        const float ly = yc - (float)y0, hy = 1.0f - ly;
        const int   y1 = min(y0 + 1, H - 1);

        const float xc = fminf(fmaxf(xs, 0.0f), (float)(W - 1));
        const int   x0 = (int)floorf(xc);
        const float lx = xc - (float)x0, hx = 1.0f - lx;
        const bool  xpair = (x0 < W - 1);

        const float wxh = xpair ? hx : (hx + lx);   // fold x-clamp into col x0
        const float wxl = xpair ? lx : 0.0f;
        const float m   = (vy && vx) ? 0.25f : 0.0f;

        const int relc = x0 - x4_lo;                // 0..18
        s_off[tid] = make_int2((y0 - y_lo) * BW + relc,
                               (y1 - y_lo) * BW + relc);
        s_wt[tid]  = make_float4(hy * wxh * m, hy * wxl * m,
                                 ly * wxh * m, ly * wxl * m);
    }

    // ---- stage exact box for 8 planes: nrows x ncol4 float4, coalesced ----
    {
        const int nrc   = nrows * ncol4;            // <= 85
        const int total = P * nrc;                  // <= 680
        const unsigned inv_nrc = 65535u / (unsigned)nrc   + 1u;  // exact for i<680
        const unsigned inv_c   = 65535u / (unsigned)ncol4 + 1u;  // exact for rem<85
        const int pbase = ((bidx * C + c) * T + (g << 3)) << 12; // elem idx (c, t0)
        for (int i = tid; i < total; i += 256) {    // ~2 iters typical
            const int p   = (int)(((unsigned)i * inv_nrc) >> 16);
            const int rem = i - p * nrc;
            const int row = (int)(((unsigned)rem * inv_c) >> 16);
            const int col = rem - row * ncol4;
            int sidx = pbase + (p << 12) + ((y_lo + row) << 6) + x4_lo + (col << 2);
            sidx = min(sidx, TOT - 4);              // array-end guard (pad col)
            const float4 v = *(const float4*)(x + sidx);
            *(float4*)&s_box[p * PSTR + row * BW + (col << 2)] = v;
        }
    }
    __syncthreads();

    // ---- Phase B: 392 outputs (1 full round + 136 tail), contiguous store ---
    const size_t obase = (size_t)(((r * C + c) * T) + (g << 3)) * NBINS;
    {
        const int oidx = tid;                       // 0..255
        const int p  = oidx / 49;
        const int pp = oidx - p * 49;
        const float* __restrict__ bx = &s_box[p * PSTR];
        float acc = 0.0f;
#pragma unroll
        for (int s = 0; s < NSAMP; ++s) {
            const int2   o = s_off[s * NBINS + pp];
            const float4 w = s_wt[s * NBINS + pp];
            acc += w.x * bx[o.x] + w.y * bx[o.x + 1] +
                   w.z * bx[o.y] + w.w * bx[o.y + 1];
        }
        out[obase + oidx] = acc;
    }
    if (tid < P * NBINS - 256) {                    // 136 tail outputs
        const int oidx = 256 + tid;
        const int p  = oidx / 49;
        const int pp = oidx - p * 49;
        const float* __restrict__ bx = &s_box[p * PSTR];
        float acc = 0.0f;
#pragma unroll
        for (int s = 0; s < NSAMP; ++s) {
            const int2   o = s_off[s * NBINS + pp];
            const float4 w = s_wt[s * NBINS + pp];
            acc += w.x * bx[o.x] + w.y * bx[o.x + 1] +
                   w.z * bx[o.y] + w.w * bx[o.y + 1];
        }
        out[obase + oidx] = acc;
    }
}

extern "C" void kernel_launch(void* const* d_in, const int* in_sizes, int n_in,
                              void* d_out, int out_size, void* d_ws, size_t ws_size,
                              hipStream_t stream) {
    const float* x    = (const float*)d_in[0];
    const float* rois = (const float*)d_in[1];
    float* out = (float*)d_out;

    // 256 channels * 64 rois * 2 t-halves = 32768 blocks, roi-inner
    roialign3d_kernel<<<dim3(32768), dim3(256), 0, stream>>>(x, rois, out);
}